// Round 10
// baseline (398.146 us; speedup 1.0000x reference)
//
#include <hip/hip_runtime.h>
#include <math.h>

// Problem constants (from reference):
constexpr int Bc = 4, Tc = 512, Cc = 768, Hc = 12, HSc = 64;
constexpr int QKVN = 3 * Cc;  // 2304
constexpr double EPSd = 1e-6;

// ---------------------------------------------------------------------------
// Split-K fp32 GEMM partial. BM=64 x BN=128 tile, 128 threads (2 waves),
// thread tile TM=16 x TN=4, BK=16. Per-lane LDS read = 80 B per 128 FLOP
// (0.625 B/FLOP) -> delivery-bound ceiling ~80% VALU (R9's 4x4 tile was 1.0
// B/FLOP -> 50%, measured 49%). Bank audit: A-frag = 2-address broadcast
// (free); B-frag b128 delivery-bound; A-scatter + B-stage writes exactly
// 2-way (free on CDNA4). Grid (1152 blocks) fits fully co-resident.
// Summation order bitwise identical to R7's proven kernel (serial k within
// slice, slices reduced in ascending order).
// ---------------------------------------------------------------------------
__global__ void __launch_bounds__(128, 2) gemm_sk(
    const float* __restrict__ X, const float* __restrict__ W,
    float* __restrict__ P, int N, int kPerSplit) {
  constexpr int BK = 16;
  __shared__ float As[BK][68];   // [k][row] transposed
  __shared__ float Bs[BK][132];  // [k][col]
  const int tid = threadIdx.x;
  const int tx = tid & 31;   // col group (TN=4)
  const int ty = tid >> 5;   // row group (TM=16)
  const int rb = blockIdx.x * 64;
  const int cb = blockIdx.y * 128;
  const int kBeg = blockIdx.z * kPerSplit;
  // staging assignments
  const int arow = tid >> 1;        // 0..63
  const int ak8 = (tid & 1) * 8;    // 0 or 8
  const int bkk = tid >> 3;         // 0..15
  const int bc16 = (tid & 7) * 16;  // 0..112
  const float* aptr = &X[(size_t)(rb + arow) * Cc + kBeg + ak8];
  const float* bptr = &W[(size_t)(kBeg + bkk) * N + cb + bc16];
  float acc[16][4];
#pragma unroll
  for (int m = 0; m < 16; ++m)
#pragma unroll
    for (int n = 0; n < 4; ++n) acc[m][n] = 0.0f;

  const int nIter = kPerSplit / BK;
  float4 a0 = *(const float4*)aptr;
  float4 a1 = *(const float4*)(aptr + 4);
  float4 b0 = *(const float4*)bptr;
  float4 b1 = *(const float4*)(bptr + 4);
  float4 b2 = *(const float4*)(bptr + 8);
  float4 b3 = *(const float4*)(bptr + 12);
  for (int it = 0; it < nIter; ++it) {
    __syncthreads();  // previous compute done reading LDS
    As[ak8 + 0][arow] = a0.x; As[ak8 + 1][arow] = a0.y;
    As[ak8 + 2][arow] = a0.z; As[ak8 + 3][arow] = a0.w;
    As[ak8 + 4][arow] = a1.x; As[ak8 + 5][arow] = a1.y;
    As[ak8 + 6][arow] = a1.z; As[ak8 + 7][arow] = a1.w;
    *(float4*)&Bs[bkk][bc16 + 0] = b0;
    *(float4*)&Bs[bkk][bc16 + 4] = b1;
    *(float4*)&Bs[bkk][bc16 + 8] = b2;
    *(float4*)&Bs[bkk][bc16 + 12] = b3;
    __syncthreads();
    if (it + 1 < nIter) {  // prefetch next stage into registers
      aptr += BK;
      bptr += (size_t)BK * N;
      a0 = *(const float4*)aptr;
      a1 = *(const float4*)(aptr + 4);
      b0 = *(const float4*)bptr;
      b1 = *(const float4*)(bptr + 4);
      b2 = *(const float4*)(bptr + 8);
      b3 = *(const float4*)(bptr + 12);
    }
#pragma unroll
    for (int kk = 0; kk < BK; ++kk) {
      float av[16];
#pragma unroll
      for (int m4 = 0; m4 < 4; ++m4) {
        const float4 af = *(const float4*)&As[kk][ty * 16 + m4 * 4];
        av[m4 * 4 + 0] = af.x; av[m4 * 4 + 1] = af.y;
        av[m4 * 4 + 2] = af.z; av[m4 * 4 + 3] = af.w;
      }
      const float4 bf = *(const float4*)&Bs[kk][tx * 4];
      const float bv[4] = {bf.x, bf.y, bf.z, bf.w};
#pragma unroll
      for (int m = 0; m < 16; ++m)
#pragma unroll
        for (int n = 0; n < 4; ++n) acc[m][n] += av[m] * bv[n];
    }
  }
  float* Pp = P + (size_t)blockIdx.z * ((size_t)2048 * N);
#pragma unroll
  for (int m = 0; m < 16; ++m) {
    const float4 o = {acc[m][0], acc[m][1], acc[m][2], acc[m][3]};
    *(float4*)&Pp[(size_t)(rb + ty * 16 + m) * N + cb + tx * 4] = o;
  }
}

// ---------------------------------------------------------------------------
// out = sum_ks P[ks] + bias (fixed order -> deterministic). float4 vectorized.
// ---------------------------------------------------------------------------
__global__ void __launch_bounds__(256) reduce_bias_kernel(
    const float* __restrict__ P, const float* __restrict__ bias,
    float* __restrict__ outp, int MN, int N, int KS) {
  const int idx4 = (blockIdx.x * 256 + threadIdx.x) * 4;
  float4 acc = *(const float4*)&P[idx4];
  for (int ks = 1; ks < KS; ++ks) {
    const float4 p = *(const float4*)&P[(size_t)ks * MN + idx4];
    acc.x += p.x; acc.y += p.y; acc.z += p.z; acc.w += p.w;
  }
  const int col = idx4 % N;
  const float4 b4 = *(const float4*)&bias[col];
  acc.x += b4.x; acc.y += b4.y; acc.z += b4.z; acc.w += b4.w;
  *(float4*)&outp[idx4] = acc;
}

// ---------------------------------------------------------------------------
// S[bh][i][j] = q_i . k_j (fp32). LOWER-TRIANGLE TILES ONLY; j>i masked in
// topk. 64x64x64 tile, 4x4 register tile, operands transposed [d][tok] in LDS.
// ---------------------------------------------------------------------------
__global__ void __launch_bounds__(256) sims_kernel(
    const float* __restrict__ qkv, float* __restrict__ S) {
  const int bh = blockIdx.y;
  const int b = bh / Hc, h = bh % Hc;
  int it = 0;
  {
    const int t = blockIdx.x;
    while ((it + 1) * (it + 2) / 2 <= t) ++it;
  }
  const int jt = blockIdx.x - it * (it + 1) / 2;
  const int tid = threadIdx.x;
  const int tx = tid & 15, ty = tid >> 4;
  __shared__ float Qs[HSc][68];
  __shared__ float Ks[HSc][68];
  const float* base = qkv + (size_t)b * Tc * QKVN + h * HSc;
  {
    const int row = tid >> 2;
    const int d0 = (tid & 3) * 16;
    const float* qrow = base + (size_t)(it * 64 + row) * QKVN;
    const float* krow = base + (size_t)(jt * 64 + row) * QKVN + Cc;
#pragma unroll
    for (int u = 0; u < 4; ++u) {
      const float4 q4 = *(const float4*)&qrow[d0 + u * 4];
      const float4 k4 = *(const float4*)&krow[d0 + u * 4];
      Qs[d0 + u * 4 + 0][row] = q4.x; Qs[d0 + u * 4 + 1][row] = q4.y;
      Qs[d0 + u * 4 + 2][row] = q4.z; Qs[d0 + u * 4 + 3][row] = q4.w;
      Ks[d0 + u * 4 + 0][row] = k4.x; Ks[d0 + u * 4 + 1][row] = k4.y;
      Ks[d0 + u * 4 + 2][row] = k4.z; Ks[d0 + u * 4 + 3][row] = k4.w;
    }
  }
  __syncthreads();
  float acc[4][4];
#pragma unroll
  for (int m = 0; m < 4; ++m)
#pragma unroll
    for (int n = 0; n < 4; ++n) acc[m][n] = 0.0f;
#pragma unroll 4
  for (int d = 0; d < HSc; ++d) {
    const float4 a4 = *(const float4*)&Qs[d][ty * 4];
    const float4 b4 = *(const float4*)&Ks[d][tx * 4];
    const float a[4] = {a4.x, a4.y, a4.z, a4.w};
    const float bv[4] = {b4.x, b4.y, b4.z, b4.w};
#pragma unroll
    for (int m = 0; m < 4; ++m)
#pragma unroll
      for (int n = 0; n < 4; ++n) acc[m][n] += a[m] * bv[n];
  }
  float* Shead = S + (size_t)bh * Tc * Tc;
#pragma unroll
  for (int m = 0; m < 4; ++m) {
    const int i = it * 64 + ty * 4 + m;
    float4 o4 = {acc[m][0], acc[m][1], acc[m][2], acc[m][3]};
    *(float4*)&Shead[(size_t)i * Tc + jt * 64 + tx * 4] = o4;
  }
}

// ---------------------------------------------------------------------------
// Top-16 per token row, one full wave per token. key=(sortable(f32)<<32)|
// (511-j) -> exact jax.lax.top_k semantics; j>i masked here (key=0).
// ---------------------------------------------------------------------------
__global__ void __launch_bounds__(256) topk_kernel(
    const float* __restrict__ S, int* __restrict__ topidx,
    unsigned* __restrict__ availB) {
  const int tid = threadIdx.x;
  const int wv = tid >> 6, lane = tid & 63;
  const int tok = blockIdx.x * 4 + wv;  // bh*512 + i
  const int i = tok & (Tc - 1);
  const float4* Sq = reinterpret_cast<const float4*>(S + (size_t)tok * Tc);
  unsigned long long key[8];
#pragma unroll
  for (int r = 0; r < 2; ++r) {
    const float4 v4 = Sq[lane * 2 + r];
    const float vv[4] = {v4.x, v4.y, v4.z, v4.w};
#pragma unroll
    for (int c = 0; c < 4; ++c) {
      const int j = lane * 8 + r * 4 + c;
      const unsigned u = __float_as_uint(vv[c]);
      const unsigned s = (u & 0x80000000u) ? ~u : (u | 0x80000000u);
      key[r * 4 + c] = (j <= i)
          ? (((unsigned long long)s << 32) | (unsigned)(511 - j))
          : 0ull;
    }
  }
  unsigned avail = 0;
  for (int m = 0; m < 16; ++m) {
    unsigned long long bk = 0;
#pragma unroll
    for (int r = 0; r < 8; ++r) bk = (key[r] > bk) ? key[r] : bk;
#pragma unroll
    for (int msk = 1; msk <= 32; msk <<= 1) {
      const unsigned long long ok = __shfl_xor(bk, msk);
      bk = (ok > bk) ? ok : bk;
    }
    const int j = 511 - (int)(unsigned)(bk & 0xFFFFFFFFull);
    const unsigned shi = (unsigned)(bk >> 32);
    if (lane == 0) topidx[(size_t)tok * 16 + m] = j & 511;
    if (shi > 0x007FFFFFu && j != i) avail |= (1u << m);
#pragma unroll
    for (int r = 0; r < 8; ++r) key[r] = (key[r] == bk) ? 0ull : key[r];
  }
  if (lane == 0) availB[tok] = avail;
}

// ---------------------------------------------------------------------------
// Greedy DPP selection, ONE token per wave, 4 lanes per candidate, all
// candidate data in REGISTERS. Incremental-Cholesky scoring (R4-R9, proven).
// ---------------------------------------------------------------------------
__global__ void __launch_bounds__(256, 4) select_kernel(
    const float* __restrict__ qkv, const int* __restrict__ topidx,
    const unsigned* __restrict__ availB, float* __restrict__ y) {
  const int tid = threadIdx.x;
  const int wv = tid >> 6, lane = tid & 63;
  const int tok = blockIdx.x * 4 + wv;  // bh*512 + i
  const int bh = tok >> 9;
  const int i = tok & (Tc - 1);
  const int b = bh / Hc;
  const int h = bh % Hc;
  const int m = lane >> 2;   // candidate 0..15
  const int q = lane & 3;    // quarter 0..3 (16 dims each)

  const float* base = qkv + (size_t)b * Tc * QKVN + h * HSc;
  const float* kbase = base + Cc;
  const float* vbase = base + 2 * Cc;

  __shared__ int selS[4][8];

  const int tidx = topidx[(size_t)tok * 16 + m];  // cluster-uniform
  unsigned avail = availB[tok];                   // wave-uniform

  // gather my candidate's quarter + k_i's quarter into registers
  float kreg[16], kireg[16];
  {
    const float* kc = kbase + (size_t)tidx * QKVN + q * 16;
    const float* ki = kbase + (size_t)i * QKVN + q * 16;
#pragma unroll
    for (int u = 0; u < 4; ++u) {
      const float4 c4 = *(const float4*)&kc[u * 4];
      const float4 i4 = *(const float4*)&ki[u * 4];
      kreg[u * 4 + 0] = c4.x; kreg[u * 4 + 1] = c4.y;
      kreg[u * 4 + 2] = c4.z; kreg[u * 4 + 3] = c4.w;
      kireg[u * 4 + 0] = i4.x; kireg[u * 4 + 1] = i4.y;
      kireg[u * 4 + 2] = i4.z; kireg[u * 4 + 3] = i4.w;
    }
  }
  // fp32 partial dots + cluster reduce (shfl_xor 1,2)
  float cnorm_f = 0.0f, c0_f = 0.0f, kii_f = 0.0f;
#pragma unroll
  for (int e = 0; e < 16; ++e) {
    cnorm_f += kreg[e] * kreg[e];
    c0_f += kreg[e] * kireg[e];
    kii_f += kireg[e] * kireg[e];
  }
  cnorm_f += __shfl_xor(cnorm_f, 1); cnorm_f += __shfl_xor(cnorm_f, 2);
  c0_f += __shfl_xor(c0_f, 1);       c0_f += __shfl_xor(c0_f, 2);
  kii_f += __shfl_xor(kii_f, 1);     kii_f += __shfl_xor(kii_f, 2);

  const double kii = (double)kii_f;
  double z[8];
#pragma unroll
  for (int t = 0; t < 8; ++t) z[t] = 0.0;
  z[0] = (double)c0_f / sqrt(kii);
  double schur = (double)cnorm_f - z[0] * z[0];
  double detS = kii;
  double cur_s = -log(kii + EPSd);
  int count = 1;
  if (lane == 0) selS[wv][0] = i;

  // greedy loop: all accept/compare decisions wave-uniform
#pragma unroll
  for (int it = 0; it < 7; ++it) {
    const double D = detS * schur + EPSd;
    const double sval = -log(D) / (double)(it + 2);
    const bool act = (avail >> m) & 1u;
    const double sorig = act ? sval : -INFINITY;
    // wave argmax over 16 candidates (4-lane clusters carry equal keys);
    // NaN acts as max (numpy argmax), ties -> lower m
    double bkey = __builtin_isnan(sorig) ? INFINITY : sorig;
    int bm = m;
#pragma unroll
    for (int msk = 1; msk <= 32; msk <<= 1) {
      const double ok2 = __shfl_xor(bkey, msk);
      const int om = __shfl_xor(bm, msk);
      const bool t2 = (ok2 > bkey) || (ok2 == bkey && om < bm);
      bkey = t2 ? ok2 : bkey;
      bm = t2 ? om : bm;
    }
    const double best_s = __shfl(sorig, bm * 4);  // original (maybe NaN)
    const bool X = (avail != 0u) && ((best_s > cur_s) || (it == 0));
    if (!X) break;  // wave-uniform: first reject -> done forever
    // cp = k_c . k_best: element shfls from the owner cluster's q-th lane
    float cp_f = 0.0f;
#pragma unroll
    for (int e = 0; e < 16; ++e) {
      const float kb = __shfl(kreg[e], bm * 4 + q);
      cp_f += kreg[e] * kb;
    }
    cp_f += __shfl_xor(cp_f, 1); cp_f += __shfl_xor(cp_f, 2);
    // z-recursion in f64 (z of candidate bm is cluster-replicated)
    const double schur_b = __shfl(schur, bm * 4);
    double sum = 0.0;
#pragma unroll
    for (int t = 0; t <= it; ++t) {
      const double zbt = __shfl(z[t], bm * 4);
      sum += z[t] * zbt;
    }
    const double znew = ((double)cp_f - sum) / sqrt(schur_b);
    z[it + 1] = znew;
    schur -= znew * znew;
    detS *= schur_b;
    cur_s = best_s;
    avail &= ~(1u << bm);
    ++count;
    const int selIdx = __shfl(tidx, bm * 4);
    if (lane == 0) selS[wv][it + 1] = selIdx;
  }

  // output = mean of selected v rows; y is [B,T,H,HS]
  double acc = 0.0;
#pragma unroll
  for (int a = 0; a < 8; ++a)
    if (a < count) acc += (double)vbase[(size_t)selS[wv][a] * QKVN + lane];
  y[(((size_t)b * Tc + i) * Hc + h) * HSc + lane] =
      (float)(acc / (double)count);
}

// ---------------------------------------------------------------------------
extern "C" void kernel_launch(void* const* d_in, const int* in_sizes, int n_in,
                              void* d_out, int out_size, void* d_ws, size_t ws_size,
                              hipStream_t stream) {
  (void)in_sizes; (void)n_in; (void)out_size; (void)ws_size;
  const float* x  = (const float*)d_in[0];
  const float* Wa = (const float*)d_in[1];
  const float* ba = (const float*)d_in[2];
  const float* Wp = (const float*)d_in[3];
  const float* bp = (const float*)d_in[4];
  float* out = (float*)d_out;

  // Workspace layout (77.2 MB total — same footprint as R5-R9):
  float* qkv = (float*)d_ws;                            // 18.87 MB
  float* y   = qkv + (size_t)Bc * Tc * QKVN;            //  6.29 MB
  int* topidx = (int*)(y + (size_t)Bc * Tc * Cc);       //  1.57 MB
  unsigned* availB = (unsigned*)(topidx + (size_t)Bc * Hc * Tc * 16);  // 98 KB
  // Region B (aliased, 50.33 MB): Pqkv (37.75) -> S (50.33) -> Pproj (37.75);
  // stream order guarantees disjoint lifetimes.
  float* regionB = (float*)(availB + (size_t)Bc * Hc * Tc);
  float* S = regionB;
  float* Pqkv = regionB;
  float* Pproj = regionB;

  const int MNqkv = Bc * Tc * QKVN;  // 4,718,592
  const int MNproj = Bc * Tc * Cc;   // 1,572,864

  // 1) qkv partials (KS=2, k-slice 384; 32x18x2 = 1152 blocks) + reduce+bias
  hipLaunchKernelGGL(gemm_sk, dim3(32, QKVN / 128, 2), dim3(128), 0,
                     stream, x, Wa, Pqkv, QKVN, 384);
  hipLaunchKernelGGL(reduce_bias_kernel, dim3(MNqkv / 1024), dim3(256), 0,
                     stream, Pqkv, ba, qkv, MNqkv, QKVN, 2);
  // 2) S = Q K^T per head, lower-triangle tiles only
  hipLaunchKernelGGL(sims_kernel, dim3(36, Bc * Hc), dim3(256), 0,
                     stream, qkv, S);
  // 3) top-16 per token
  hipLaunchKernelGGL(topk_kernel, dim3(Bc * Hc * Tc / 4), dim3(256), 0,
                     stream, S, topidx, availB);
  // 4) greedy DPP, 1 token/wave, register-resident candidates
  hipLaunchKernelGGL(select_kernel, dim3(Bc * Hc * Tc / 4), dim3(256), 0,
                     stream, qkv, topidx, availB, y);
  // 5) proj partials (KS=6, k-slice 128; 32x6x6 = 1152 blocks) + reduce+bias
  hipLaunchKernelGGL(gemm_sk, dim3(32, Cc / 128, 6), dim3(128), 0,
                     stream, y, Wp, Pproj, Cc, 128);
  hipLaunchKernelGGL(reduce_bias_kernel, dim3(MNproj / 1024), dim3(256), 0,
                     stream, Pproj, bp, out, MNproj, Cc, 6);
}

// Round 11
// 379.000 us; speedup vs baseline: 1.0505x; 1.0505x over previous
//
#include <hip/hip_runtime.h>
#include <math.h>

// Problem constants (from reference):
constexpr int Bc = 4, Tc = 512, Cc = 768, Hc = 12, HSc = 64;
constexpr int QKVN = 3 * Cc;  // 2304
constexpr double EPSd = 1e-6;

// ---------------------------------------------------------------------------
// fp32 GEMM, BM=64 x BN=64, 128 threads (2 waves), thread tile TM=8 x TN=4
// (rows ty*4+{0..3} and ty*4+32+{0..3}), BK=16. Per-lane LDS = 48 B per 64
// FLOP (0.75 B/FLOP) -> delivery cap 66% VALU (R9's 4x4 was 1.0 -> 50%,
// measured 49%). LDS stride 66 (== 2 mod 32), audited per instruction:
//   A-frag reads: 4 unique addrs on disjoint banks (broadcast, free)
//   B-frag reads: 2-way distinct-addr (free on CDNA4, m136)
//   A-scatter writes: k8 pair diff = 8*66=528 == 16 mod 32 -> 2-way (free)
//   B-stage float4 writes: 2-way (free)
// VGPR ~82 -> >=4 waves/SIMD; qkv grid 1152 light blocks, all co-resident.
// k ascending within slice; WRITE_PARTIAL=false adds bias directly.
// Summation order bitwise identical to R9's passing gemm64.
// ---------------------------------------------------------------------------
template <bool WRITE_PARTIAL>
__global__ void __launch_bounds__(128, 4) gemm_t84(
    const float* __restrict__ X, const float* __restrict__ W,
    const float* __restrict__ bias, float* __restrict__ outp,
    int N, int kPerSplit) {
  constexpr int BK = 16;
  __shared__ float As[BK][66];  // [k][row] transposed
  __shared__ float Bs[BK][66];  // [k][col]
  const int tid = threadIdx.x;
  const int tx = tid & 15;   // col group: cols tx*4..tx*4+3
  const int ty = tid >> 4;   // row group 0..7
  const int rb = blockIdx.x * 64;
  const int cb = blockIdx.y * 64;
  const int kBeg = blockIdx.z * kPerSplit;
  // staging assignments (each thread: 2 float4 of A, 2 float4 of B)
  const int arow = tid >> 1;        // 0..63
  const int ak8 = (tid & 1) * 8;    // 0 or 8
  const int bkk = tid >> 3;         // 0..15
  const int bc8 = (tid & 7) * 8;    // 0..56
  const float* aptr = &X[(size_t)(rb + arow) * Cc + kBeg + ak8];
  const float* bptr = &W[(size_t)(kBeg + bkk) * N + cb + bc8];
  float acc[8][4];
#pragma unroll
  for (int m = 0; m < 8; ++m)
#pragma unroll
    for (int n = 0; n < 4; ++n) acc[m][n] = 0.0f;

  const int nIter = kPerSplit / BK;
  float4 a0 = *(const float4*)aptr;
  float4 a1 = *(const float4*)(aptr + 4);
  float4 b0 = *(const float4*)bptr;
  float4 b1 = *(const float4*)(bptr + 4);
  for (int it = 0; it < nIter; ++it) {
    __syncthreads();  // previous compute done reading LDS
    As[ak8 + 0][arow] = a0.x; As[ak8 + 1][arow] = a0.y;
    As[ak8 + 2][arow] = a0.z; As[ak8 + 3][arow] = a0.w;
    As[ak8 + 4][arow] = a1.x; As[ak8 + 5][arow] = a1.y;
    As[ak8 + 6][arow] = a1.z; As[ak8 + 7][arow] = a1.w;
    *(float4*)&Bs[bkk][bc8] = b0;
    *(float4*)&Bs[bkk][bc8 + 4] = b1;
    __syncthreads();
    if (it + 1 < nIter) {  // prefetch next stage into registers
      aptr += BK;
      bptr += (size_t)BK * N;
      a0 = *(const float4*)aptr;
      a1 = *(const float4*)(aptr + 4);
      b0 = *(const float4*)bptr;
      b1 = *(const float4*)(bptr + 4);
    }
#pragma unroll
    for (int kk = 0; kk < BK; ++kk) {
      const float4 af0 = *(const float4*)&As[kk][ty * 4];
      const float4 af1 = *(const float4*)&As[kk][ty * 4 + 32];
      const float4 bf = *(const float4*)&Bs[kk][tx * 4];
      const float av[8] = {af0.x, af0.y, af0.z, af0.w,
                           af1.x, af1.y, af1.z, af1.w};
      const float bv[4] = {bf.x, bf.y, bf.z, bf.w};
#pragma unroll
      for (int m = 0; m < 8; ++m)
#pragma unroll
        for (int n = 0; n < 4; ++n) acc[m][n] += av[m] * bv[n];
    }
  }
  if (WRITE_PARTIAL) {
    float* Pp = outp + (size_t)blockIdx.z * ((size_t)2048 * N);
#pragma unroll
    for (int m = 0; m < 8; ++m) {
      const int row = rb + ty * 4 + (m & 3) + (m >> 2) * 32;
      const float4 o = {acc[m][0], acc[m][1], acc[m][2], acc[m][3]};
      *(float4*)&Pp[(size_t)row * N + cb + tx * 4] = o;
    }
  } else {
    const float4 b4 = *(const float4*)&bias[cb + tx * 4];
#pragma unroll
    for (int m = 0; m < 8; ++m) {
      const int row = rb + ty * 4 + (m & 3) + (m >> 2) * 32;
      const float4 o = {acc[m][0] + b4.x, acc[m][1] + b4.y,
                        acc[m][2] + b4.z, acc[m][3] + b4.w};
      *(float4*)&outp[(size_t)row * N + cb + tx * 4] = o;
    }
  }
}

// NOTE: thread's 8 rows are ty*4+{0..3} and ty*4+32+{0..3}; acc[m] maps via
// row = ty*4 + (m&3) + (m>>2)*32, and av[] loads match that order. But the
// FMA loop above fills acc[m] with av[m] where av[0..3]=rows ty*4+{0..3},
// av[4..7]=rows ty*4+32+{0..3} -> epilogue mapping row(m) is consistent.

// ---------------------------------------------------------------------------
// out = sum_ks P[ks] + bias (fixed order -> deterministic). float4 vectorized.
// ---------------------------------------------------------------------------
__global__ void __launch_bounds__(256) reduce_bias_kernel(
    const float* __restrict__ P, const float* __restrict__ bias,
    float* __restrict__ outp, int MN, int N, int KS) {
  const int idx4 = (blockIdx.x * 256 + threadIdx.x) * 4;
  float4 acc = *(const float4*)&P[idx4];
  for (int ks = 1; ks < KS; ++ks) {
    const float4 p = *(const float4*)&P[(size_t)ks * MN + idx4];
    acc.x += p.x; acc.y += p.y; acc.z += p.z; acc.w += p.w;
  }
  const int col = idx4 % N;
  const float4 b4 = *(const float4*)&bias[col];
  acc.x += b4.x; acc.y += b4.y; acc.z += b4.z; acc.w += b4.w;
  *(float4*)&outp[idx4] = acc;
}

// ---------------------------------------------------------------------------
// S[bh][i][j] = q_i . k_j (fp32). LOWER-TRIANGLE TILES ONLY; j>i masked in
// the fused topk. 64x64x64 tile, 4x4 register tile, operands [d][tok] in LDS.
// ---------------------------------------------------------------------------
__global__ void __launch_bounds__(256) sims_kernel(
    const float* __restrict__ qkv, float* __restrict__ S) {
  const int bh = blockIdx.y;
  const int b = bh / Hc, h = bh % Hc;
  int it = 0;
  {
    const int t = blockIdx.x;
    while ((it + 1) * (it + 2) / 2 <= t) ++it;
  }
  const int jt = blockIdx.x - it * (it + 1) / 2;
  const int tid = threadIdx.x;
  const int tx = tid & 15, ty = tid >> 4;
  __shared__ float Qs[HSc][68];
  __shared__ float Ks[HSc][68];
  const float* base = qkv + (size_t)b * Tc * QKVN + h * HSc;
  {
    const int row = tid >> 2;
    const int d0 = (tid & 3) * 16;
    const float* qrow = base + (size_t)(it * 64 + row) * QKVN;
    const float* krow = base + (size_t)(jt * 64 + row) * QKVN + Cc;
#pragma unroll
    for (int u = 0; u < 4; ++u) {
      const float4 q4 = *(const float4*)&qrow[d0 + u * 4];
      const float4 k4 = *(const float4*)&krow[d0 + u * 4];
      Qs[d0 + u * 4 + 0][row] = q4.x; Qs[d0 + u * 4 + 1][row] = q4.y;
      Qs[d0 + u * 4 + 2][row] = q4.z; Qs[d0 + u * 4 + 3][row] = q4.w;
      Ks[d0 + u * 4 + 0][row] = k4.x; Ks[d0 + u * 4 + 1][row] = k4.y;
      Ks[d0 + u * 4 + 2][row] = k4.z; Ks[d0 + u * 4 + 3][row] = k4.w;
    }
  }
  __syncthreads();
  float acc[4][4];
#pragma unroll
  for (int m = 0; m < 4; ++m)
#pragma unroll
    for (int n = 0; n < 4; ++n) acc[m][n] = 0.0f;
#pragma unroll 4
  for (int d = 0; d < HSc; ++d) {
    const float4 a4 = *(const float4*)&Qs[d][ty * 4];
    const float4 b4 = *(const float4*)&Ks[d][tx * 4];
    const float a[4] = {a4.x, a4.y, a4.z, a4.w};
    const float bv[4] = {b4.x, b4.y, b4.z, b4.w};
#pragma unroll
    for (int m = 0; m < 4; ++m)
#pragma unroll
      for (int n = 0; n < 4; ++n) acc[m][n] += a[m] * bv[n];
  }
  float* Shead = S + (size_t)bh * Tc * Tc;
#pragma unroll
  for (int m = 0; m < 4; ++m) {
    const int i = it * 64 + ty * 4 + m;
    float4 o4 = {acc[m][0], acc[m][1], acc[m][2], acc[m][3]};
    *(float4*)&Shead[(size_t)i * Tc + jt * 64 + tx * 4] = o4;
  }
}

// ---------------------------------------------------------------------------
// FUSED top-16 + greedy DPP selection: one wave per token (4 tokens/block).
// Phase 1 (ex-topk): u64 keys = (sortable(f32)<<32)|(511-j), j>i masked ->
// exact jax.lax.top_k semantics; candidate index kept in the owning 4-lane
// cluster's register (no LDS/global round-trip). Phase 2: incremental-
// Cholesky scoring, byte-identical math to R9/R10's proven select_kernel.
// ---------------------------------------------------------------------------
__global__ void __launch_bounds__(256, 4) topk_select_kernel(
    const float* __restrict__ qkv, const float* __restrict__ S,
    float* __restrict__ y) {
  const int tid = threadIdx.x;
  const int wv = tid >> 6, lane = tid & 63;
  const int tok = blockIdx.x * 4 + wv;  // bh*512 + i
  const int bh = tok >> 9;
  const int i = tok & (Tc - 1);
  const int b = bh / Hc;
  const int h = bh % Hc;
  const int m = lane >> 2;   // candidate 0..15
  const int q = lane & 3;    // quarter 0..3 (16 dims each)

  const float* base = qkv + (size_t)b * Tc * QKVN + h * HSc;
  const float* kbase = base + Cc;
  const float* vbase = base + 2 * Cc;

  __shared__ int selS[4][8];

  // ---- phase 1: top-16 scan over the precomputed S row ----
  const float4* Sq = reinterpret_cast<const float4*>(S + (size_t)tok * Tc);
  unsigned long long key[8];
#pragma unroll
  for (int r = 0; r < 2; ++r) {
    const float4 v4 = Sq[lane * 2 + r];
    const float vv[4] = {v4.x, v4.y, v4.z, v4.w};
#pragma unroll
    for (int c = 0; c < 4; ++c) {
      const int j = lane * 8 + r * 4 + c;
      const unsigned u = __float_as_uint(vv[c]);
      const unsigned s = (u & 0x80000000u) ? ~u : (u | 0x80000000u);
      key[r * 4 + c] = (j <= i)
          ? (((unsigned long long)s << 32) | (unsigned)(511 - j))
          : 0ull;
    }
  }
  unsigned avail = 0;
  int tidx = 0;  // candidate m's token index, kept by its 4-lane cluster
  for (int mm = 0; mm < 16; ++mm) {
    unsigned long long bk = 0;
#pragma unroll
    for (int r = 0; r < 8; ++r) bk = (key[r] > bk) ? key[r] : bk;
#pragma unroll
    for (int msk = 1; msk <= 32; msk <<= 1) {
      const unsigned long long ok = __shfl_xor(bk, msk);
      bk = (ok > bk) ? ok : bk;
    }
    const int j = (511 - (int)(unsigned)(bk & 0xFFFFFFFFull)) & 511;
    const unsigned shi = (unsigned)(bk >> 32);
    if (m == mm) tidx = j;
    if (shi > 0x007FFFFFu && j != i) avail |= (1u << mm);
#pragma unroll
    for (int r = 0; r < 8; ++r) key[r] = (key[r] == bk) ? 0ull : key[r];
  }

  // ---- phase 2: greedy DPP (identical math to R9/R10 select_kernel) ----
  float kreg[16], kireg[16];
  {
    const float* kc = kbase + (size_t)tidx * QKVN + q * 16;
    const float* ki = kbase + (size_t)i * QKVN + q * 16;
#pragma unroll
    for (int u = 0; u < 4; ++u) {
      const float4 c4 = *(const float4*)&kc[u * 4];
      const float4 i4 = *(const float4*)&ki[u * 4];
      kreg[u * 4 + 0] = c4.x; kreg[u * 4 + 1] = c4.y;
      kreg[u * 4 + 2] = c4.z; kreg[u * 4 + 3] = c4.w;
      kireg[u * 4 + 0] = i4.x; kireg[u * 4 + 1] = i4.y;
      kireg[u * 4 + 2] = i4.z; kireg[u * 4 + 3] = i4.w;
    }
  }
  float cnorm_f = 0.0f, c0_f = 0.0f, kii_f = 0.0f;
#pragma unroll
  for (int e = 0; e < 16; ++e) {
    cnorm_f += kreg[e] * kreg[e];
    c0_f += kreg[e] * kireg[e];
    kii_f += kireg[e] * kireg[e];
  }
  cnorm_f += __shfl_xor(cnorm_f, 1); cnorm_f += __shfl_xor(cnorm_f, 2);
  c0_f += __shfl_xor(c0_f, 1);       c0_f += __shfl_xor(c0_f, 2);
  kii_f += __shfl_xor(kii_f, 1);     kii_f += __shfl_xor(kii_f, 2);

  const double kii = (double)kii_f;
  double z[8];
#pragma unroll
  for (int t = 0; t < 8; ++t) z[t] = 0.0;
  z[0] = (double)c0_f / sqrt(kii);
  double schur = (double)cnorm_f - z[0] * z[0];
  double detS = kii;
  double cur_s = -log(kii + EPSd);
  int count = 1;
  if (lane == 0) selS[wv][0] = i;

#pragma unroll
  for (int it = 0; it < 7; ++it) {
    const double D = detS * schur + EPSd;
    const double sval = -log(D) / (double)(it + 2);
    const bool act = (avail >> m) & 1u;
    const double sorig = act ? sval : -INFINITY;
    double bkey = __builtin_isnan(sorig) ? INFINITY : sorig;
    int bm = m;
#pragma unroll
    for (int msk = 1; msk <= 32; msk <<= 1) {
      const double ok2 = __shfl_xor(bkey, msk);
      const int om = __shfl_xor(bm, msk);
      const bool t2 = (ok2 > bkey) || (ok2 == bkey && om < bm);
      bkey = t2 ? ok2 : bkey;
      bm = t2 ? om : bm;
    }
    const double best_s = __shfl(sorig, bm * 4);  // original (maybe NaN)
    const bool X = (avail != 0u) && ((best_s > cur_s) || (it == 0));
    if (!X) break;  // wave-uniform: first reject -> done forever
    float cp_f = 0.0f;
#pragma unroll
    for (int e = 0; e < 16; ++e) {
      const float kb = __shfl(kreg[e], bm * 4 + q);
      cp_f += kreg[e] * kb;
    }
    cp_f += __shfl_xor(cp_f, 1); cp_f += __shfl_xor(cp_f, 2);
    const double schur_b = __shfl(schur, bm * 4);
    double sum = 0.0;
#pragma unroll
    for (int t = 0; t <= it; ++t) {
      const double zbt = __shfl(z[t], bm * 4);
      sum += z[t] * zbt;
    }
    const double znew = ((double)cp_f - sum) / sqrt(schur_b);
    z[it + 1] = znew;
    schur -= znew * znew;
    detS *= schur_b;
    cur_s = best_s;
    avail &= ~(1u << bm);
    ++count;
    const int selIdx = __shfl(tidx, bm * 4);
    if (lane == 0) selS[wv][it + 1] = selIdx;
  }

  // output = mean of selected v rows; y is [B,T,H,HS]
  double acc = 0.0;
#pragma unroll
  for (int a = 0; a < 8; ++a)
    if (a < count) acc += (double)vbase[(size_t)selS[wv][a] * QKVN + lane];
  y[(((size_t)b * Tc + i) * Hc + h) * HSc + lane] =
      (float)(acc / (double)count);
}

// ---------------------------------------------------------------------------
extern "C" void kernel_launch(void* const* d_in, const int* in_sizes, int n_in,
                              void* d_out, int out_size, void* d_ws, size_t ws_size,
                              hipStream_t stream) {
  (void)in_sizes; (void)n_in; (void)out_size; (void)ws_size;
  const float* x  = (const float*)d_in[0];
  const float* Wa = (const float*)d_in[1];
  const float* ba = (const float*)d_in[2];
  const float* Wp = (const float*)d_in[3];
  const float* bp = (const float*)d_in[4];
  float* out = (float*)d_out;

  // Workspace layout (75.5 MB):
  float* qkv = (float*)d_ws;                            // 18.87 MB
  float* y   = qkv + (size_t)Bc * Tc * QKVN;            //  6.29 MB
  // Region B (aliased, 50.33 MB): S (50.33) -> Pproj (18.87);
  // stream order guarantees disjoint lifetimes (S dead after topk_select).
  float* regionB = y + (size_t)Bc * Tc * Cc;
  float* S = regionB;
  float* Pproj = regionB;

  const int MNproj = Bc * Tc * Cc;   // 1,572,864

  // 1) qkv = x @ W_attn + b_attn  (KS=1: 32x36 = 1152 light blocks, k=768)
  hipLaunchKernelGGL((gemm_t84<false>), dim3(32, QKVN / 64, 1), dim3(128), 0,
                     stream, x, Wa, ba, qkv, QKVN, Cc);
  // 2) S = Q K^T per head, lower-triangle tiles only
  hipLaunchKernelGGL(sims_kernel, dim3(36, Bc * Hc), dim3(256), 0,
                     stream, qkv, S);
  // 3) fused top-16 + greedy DPP (1 wave/token)
  hipLaunchKernelGGL(topk_select_kernel, dim3(Bc * Hc * Tc / 4), dim3(256), 0,
                     stream, qkv, S, y);
  // 4) proj partials (KS=3, k-slice 256; 32x12x3 = 1152 blocks) + reduce+bias
  hipLaunchKernelGGL((gemm_t84<true>), dim3(32, Cc / 64, 3), dim3(128), 0,
                     stream, y, Wp, nullptr, Pproj, Cc, 256);
  hipLaunchKernelGGL(reduce_bias_kernel, dim3(MNproj / 1024), dim3(256), 0,
                     stream, Pproj, bp, out, MNproj, Cc, 3);
}